// Round 9
// baseline (12655.796 us; speedup 1.0000x reference)
//
#include <hip/hip_runtime.h>
#include <stdint.h>

// LSTM: B=256, T=1024, I=64, H=256, O=1. fp32 in/out, bf16 MFMA internally.
//
// Round-20: DELETE the communication. R13-R19 proved (a) the MALL
// round-trip + detect jitter costs ~2000+ cy/step in every topology, and
// (b) full-gate register-resident weights never fit (512thr->128 VGPR cap,
// 256thr->248; wf needs 320+ -> spilled every round). Root fix: a block
// that owns ALL 256 h for a slice of BATCHES has zero cross-block
// recurrence. Weights can't be register-resident (655KB bf16) but they are
// STATIC and SHARED: stream them from L2 every step like a GEMM B-operand.
//
// Topology: 16 blocks x 1024 thr; block = 16 batches (m=16, full MFMA m
// utilization, no lane duplication). 2 blocks/XCD -> 655KB/step streamed
// from a 4MB XCD L2 (resident working set) ~690cy, under the 776cy MFMA
// floor (640 MFMA/block/step). 4 waves/SIMD hide L2 latency (rolling
// 3-deep weight slots, aggregate ~32 frags in flight/SIMD). LDS holds only
// h (8.7KB). No tags, no polls, no atomics - deterministic.
//
// prep kernel: pre-packs W_ih|W_hh rows into bf16 MFMA B-fragments in ws
// (one-time; avoids 320 f32->bf16 cvts/lane/step). Frag (wv,j,kc), 1KB
// each, fid = (wv*4+j)*10+kc; lane l holds row j*256+wv*16+(l&15),
// k = kc*32+(l>>4)*8..+7 (k<64 -> W_ih, else W_hh[k-64]).
//
// Main per step (wave wv owns hid = wv*16+ln, ALL 4 gates j):
//   a0,a1 = x_t frags (prefetched t+1); h frags kc2..9 from swizzled LDS;
//   acc[j] += mfma(a_kc, w[j][kc]) over 10 kc (rolling w0/w1/w2 slots,
//   loaded 2 kc-groups ahead; next step's kc0/kc1 issued during update);
//   in-register i,f,g,o -> c,h (lane holds batches m=lk*4+r of its hid);
//   BARRIER A; write h(t+1) bf16 pairs to h_lds (shfl-packed dwords);
//   BARRIER B. t=1023 additionally stores h to ws for the fc kernel.
//
// h_lds swizzle [HW, G4]: logical 16B unit u of batch-row b lives at
// physical unit (u + 3*b) & 31 (row = 34 units, HROW=272 ush). Reader
// bank-quad = (34b + u + 3b) % 8 = (5b + u) % 8, 5 coprime 8 -> exactly 8
// lanes per quad = uniform = conflict-free b128 reads. Writer uses the
// same key (3 * batch) -> consistent.
//
// ws layout (exactly 768KB, same footprint as prior rounds):
//   [0, 640KB): 640 weight frags; [640KB, 768KB): final h bf16 [256][256].

#define T_ 1024
#define I_ 64
#define H_ 256
#define NBLK 16
#define HROW 272                      /* ushorts per h row (544B, 34 units) */
#define WFRAG_US 512                  /* ushorts per fragment (1KB) */
#define NFRAG 640
#define H_OFF_US (NFRAG * WFRAG_US)   /* 327680 ushorts = 640KB */

typedef float floatx4 __attribute__((ext_vector_type(4)));
typedef __bf16 bf16x8 __attribute__((ext_vector_type(8)));
typedef unsigned short ushortx8 __attribute__((ext_vector_type(8)));
typedef unsigned int uint32;

__device__ __forceinline__ float bf2f(uint32 u16) {
  uint32 u = u16 << 16;
  return __builtin_bit_cast(float, u);
}
__device__ __forceinline__ bf16x8 packbf8(floatx4 a, floatx4 b) {
  bf16x8 r;
  r[0] = (__bf16)a[0]; r[1] = (__bf16)a[1];
  r[2] = (__bf16)a[2]; r[3] = (__bf16)a[3];
  r[4] = (__bf16)b[0]; r[5] = (__bf16)b[1];
  r[6] = (__bf16)b[2]; r[7] = (__bf16)b[3];
  return r;
}
__device__ __forceinline__ float fast_sig(float v) {
  return 1.0f / (1.0f + __expf(-v));
}
__device__ __forceinline__ float fast_tanh(float v) {
  float e = __expf(2.0f * v);
  return 1.0f - 2.0f / (e + 1.0f);
}

// ---- one-time weight pre-pack: fp32 W -> bf16 MFMA B-fragments in ws ----
__global__ void lstm_prep(const float* __restrict__ W_ih,
                          const float* __restrict__ W_hh,
                          unsigned short* __restrict__ ws) {
  const int gid = blockIdx.x * 256 + threadIdx.x;   // 0..40959
  const int fid = gid >> 6, lane = gid & 63;
  const int wv = fid / 40;
  const int j = (fid / 10) & 3;
  const int kc = fid % 10;
  const int row = j * 256 + wv * 16 + (lane & 15);
  const int k = kc * 32 + (lane >> 4) * 8;
  const float* src = (k < I_) ? (W_ih + (size_t)row * I_ + k)
                              : (W_hh + (size_t)row * H_ + (k - I_));
  floatx4 f0 = *(const floatx4*)src;
  floatx4 f1 = *(const floatx4*)(src + 4);
  *(bf16x8*)(ws + (size_t)fid * WFRAG_US + lane * 8) = packbf8(f0, f1);
}

__global__ __launch_bounds__(1024, 4) void lstm_main(
    const float* __restrict__ x, const float* __restrict__ b_ih,
    const float* __restrict__ b_hh, unsigned short* __restrict__ ws) {
  const int tid = threadIdx.x;
  const int blk = blockIdx.x;
  const int wv = tid >> 6;    // wave 0..15: owns hid = wv*16 + ln, gates j
  const int lane = tid & 63;
  const int ln = lane & 15;   // A row (batch) / C col (hid)
  const int lk = lane >> 4;   // k-subgroup / C row group

  __shared__ __align__(16) unsigned short h_lds[16][HROW];
  unsigned short* const hflat = &h_lds[0][0];

  {  // h_0 = 0 (also clears pad)
    uint32* p = (uint32*)hflat;
    for (int i = tid; i < 16 * HROW / 2; i += 1024) p[i] = 0u;
  }

  float bias[4];
#pragma unroll
  for (int j = 0; j < 4; ++j) {
    const int row = j * 256 + wv * 16 + ln;
    bias[j] = b_ih[row] + b_hh[row];
  }

  const unsigned short* wb = ws + (size_t)(wv * 40) * WFRAG_US + lane * 8;
  const float* xrow = x + ((size_t)(blk * 16 + ln)) * T_ * I_ + lk * 8;

  const int s0 = lk + 3 * ln;         // reader swizzle: phys = (C + s0)&31
  const int lnbase = ln * HROW;       // reader row base (ushort)
  const int ul = wv * 2 + (ln >> 3);  // writer logical unit of this hid

  floatx4 c_reg = (floatx4){0.f, 0.f, 0.f, 0.f};

  // preload x_0
  floatx4 xf0, xf1, xf2, xf3;
  xf0 = *(const floatx4*)(xrow);
  xf1 = *(const floatx4*)(xrow + 4);
  xf2 = *(const floatx4*)(xrow + 32);
  xf3 = *(const floatx4*)(xrow + 36);

  // rolling weight slots (all indices compile-time: rule #20)
  bf16x8 w0[4], w1[4], w2[4];
#define LDW(SLOT, KC)                                                      \
  _Pragma("unroll") for (int j = 0; j < 4; ++j) SLOT[j] =                  \
      *(const bf16x8*)(wb + (j * 10 + (KC)) * WFRAG_US);
#define MFMA4(A, W)                                                        \
  _Pragma("unroll") for (int j = 0; j < 4; ++j) acc[j] =                   \
      __builtin_amdgcn_mfma_f32_16x16x32_bf16((A), (W)[j], acc[j], 0, 0, 0);
#define HREAD(KC)                                                          \
  __builtin_bit_cast(bf16x8,                                               \
      *(const ushortx8*)(hflat + lnbase +                                  \
                         (((((KC) - 2) * 4 + s0) & 31) << 3)))

  LDW(w0, 0)
  LDW(w1, 1)

  __syncthreads();

#pragma unroll 1
  for (int t = 0; t < T_; ++t) {
    bf16x8 a0 = packbf8(xf0, xf1);
    bf16x8 a1 = packbf8(xf2, xf3);
    {  // prefetch x_{t+1} (clamped)
      const int tn = (t + 1 < T_) ? (t + 1) : t;
      const float* src = xrow + (size_t)tn * I_;
      xf0 = *(const floatx4*)(src);
      xf1 = *(const floatx4*)(src + 4);
      xf2 = *(const floatx4*)(src + 32);
      xf3 = *(const floatx4*)(src + 36);
    }

    floatx4 acc[4];
#pragma unroll
    for (int j = 0; j < 4; ++j)
      acc[j] = (floatx4){bias[j], bias[j], bias[j], bias[j]};

    // K-loop: kc uses slot kc%3; slot for kc+2 issued 2 groups ahead.
    LDW(w2, 2) MFMA4(a0, w0)
    LDW(w0, 3) MFMA4(a1, w1)
    { bf16x8 a = HREAD(2); LDW(w1, 4) MFMA4(a, w2) }
    { bf16x8 a = HREAD(3); LDW(w2, 5) MFMA4(a, w0) }
    { bf16x8 a = HREAD(4); LDW(w0, 6) MFMA4(a, w1) }
    { bf16x8 a = HREAD(5); LDW(w1, 7) MFMA4(a, w2) }
    { bf16x8 a = HREAD(6); LDW(w2, 8) MFMA4(a, w0) }
    { bf16x8 a = HREAD(7); LDW(w0, 9) MFMA4(a, w1) }
    { bf16x8 a = HREAD(8); MFMA4(a, w2) }
    { bf16x8 a = HREAD(9); MFMA4(a, w0) }

    // in-register nonlinearity + c update (all 64 lanes valid: m=lk*4+r)
    floatx4 iv, fv, gv, ov;
#pragma unroll
    for (int r = 0; r < 4; ++r) {
      iv[r] = fast_sig(acc[0][r]);
      fv[r] = fast_sig(acc[1][r]);
      gv[r] = fast_tanh(acc[2][r]);
      ov[r] = fast_sig(acc[3][r]);
    }
    c_reg = fv * c_reg + iv * gv;

    __syncthreads();  // A: all h(t) LDS reads complete (implied lgkm wait)

    LDW(w0, 0)  // next step's first weight groups (static addrs, no hazard)
    LDW(w1, 1)

#pragma unroll
    for (int r = 0; r < 4; ++r) {
      float hv = ov[r] * fast_tanh(c_reg[r]);
      unsigned short hb = __builtin_bit_cast(unsigned short, (__bf16)hv);
      int pv = __shfl_xor((int)hb, 1);  // partner ln^1: hid+1, same (lk,r)
      if ((ln & 1) == 0) {
        const int m = lk * 4 + r;  // batch row
        uint32 dword = (uint32)hb | ((uint32)(unsigned short)pv << 16);
        const int phys = (ul + 3 * m) & 31;  // writer swizzle, same key
        *(uint32*)(hflat + m * HROW + (phys << 3) + (ln & 7)) = dword;
        if (t == T_ - 1) {
          *(uint32*)(ws + H_OFF_US + ((size_t)(blk * 16 + m) << 8) +
                     wv * 16 + ln) = dword;
        }
      }
    }
    __syncthreads();  // B: h(t+1) ready in LDS
  }
#undef LDW
#undef MFMA4
#undef HREAD
}

// out[b] = dot(h_T[b], fc_w) + fc_b. h_T is bf16 in ws (kernel-boundary
// ordering on the stream guarantees visibility; no atomics needed).
__global__ void lstm_fc(const unsigned short* __restrict__ ws,
                        const float* __restrict__ fc_w,
                        const float* __restrict__ fc_b,
                        float* __restrict__ out) {
  const int b = threadIdx.x;
  const unsigned short* hp = ws + H_OFF_US + ((size_t)b << 8);
  float sum = fc_b[0];
#pragma unroll 4
  for (int d0 = 0; d0 < 256; d0 += 8) {
    ushortx8 v = *(const ushortx8*)(hp + d0);
#pragma unroll
    for (int e = 0; e < 8; ++e) sum += bf2f((uint32)v[e]) * fc_w[d0 + e];
  }
  out[b] = sum;
}

extern "C" void kernel_launch(void* const* d_in, const int* in_sizes, int n_in,
                              void* d_out, int out_size, void* d_ws,
                              size_t ws_size, hipStream_t stream) {
  const float* x    = (const float*)d_in[0];
  const float* W_ih = (const float*)d_in[1];
  const float* W_hh = (const float*)d_in[2];
  const float* b_ih = (const float*)d_in[3];
  const float* b_hh = (const float*)d_in[4];
  const float* fc_w = (const float*)d_in[5];
  const float* fc_b = (const float*)d_in[6];
  float* out = (float*)d_out;

  unsigned short* ws = (unsigned short*)d_ws;  // 640KB frags + 128KB h = 768KB

  lstm_prep<<<dim3(160), dim3(256), 0, stream>>>(W_ih, W_hh, ws);
  lstm_main<<<dim3(NBLK), dim3(1024), 0, stream>>>(x, b_ih, b_hh, ws);
  lstm_fc<<<dim3(1), dim3(256), 0, stream>>>(ws, fc_w, fc_b, out);
}

// Round 10
// 2485.710 us; speedup vs baseline: 5.0914x; 5.0914x over previous
//
#include <hip/hip_runtime.h>
#include <stdint.h>

// LSTM: B=256, T=1024, I=64, H=256, O=1. fp32 in/out, bf16 MFMA internally.
//
// Round-21: 4-QUARTER split - the partition the register allocator will
// actually grant. Ledger: 512thr -> 128 VGPR cap (R15/R18); 256thr -> ~248
// granted (R19 needed 400 -> spilled, 4060us); R20 streaming hit the
// per-CU L2 port wall (640KB/step / ~56B/cy = 11.7k cy/step = measured
// 12.4us/step); R11's 80-VGPR weights ran clean. Here: 128 blocks = 32
// groups x 4 quarters x 256 thr; wave owns 64 rows (ALL 4 gates x 16 hid)
// -> wf[4][10] = 160 VGPRs of weights, ~230 total <= 248. Zero per-step
// weight traffic. Fan-in 7->3.
//
// Rule-#20 (R16 lesson): kc slot order is reordered PER BLOCK at load time
// so all wf indices are compile-time: slot 0..1 = x (W_ih), 2..3 =
// OWN-quarter W_hh cols, 4..9 = peer quarters (q+1,q+2,q+3 cyclic). The
// quarter-dependence lives only in load/LDS ADDRESSES.
//
// Pipelined recurrence (R16 structure): Phase A (bias + x + own-quarter:
// 16 MFMA/wave) runs under the in-flight poll; Phase C (peer quarters: 24
// MFMA/wave) + in-register c/h update + publish sit on the serial
// publish->MALL->detect cycle. x prefetched one step ahead (clamped).
//
// Communication: R11/R13-verified relaxed AGENT-scope (MALL) 8B units
// {2xbf16 h pair, tag=step}. Quiet pipelined poll (first probes issued
// before Phase A; reloads issued BEFORE s_sleep(1); satisfied lanes stop
// loading; SENT_CAP dead-latch => wrong-answer-not-hang). Tag poison
// 0xAAAAAAAA != live tags 1..1024 => no ws init. Final h (tag 1024) ->
// separate never-polled clean region at 2*UPP (R13-verified).
// Parity/staleness: tag-t units (parity t&1) are overwritten by tag t+2
// only after the writer's poll(t+1), which needs every peer's publish
// (t+1), which follows that peer's poll(t) -> no consumer still needs tag
// t. Cross-run staleness killed by exact-tag match + monotone overwrite.
//
// LDS: h_lds[2][8][272] double buffer (8.7KB). iter t: Phase A reads own
// cols of buf[t&1] (written before END-barrier(t-1)); capture writes PEER
// cols of buf[t&1] (disjoint); MID-barrier; Phase C reads peer cols;
// update writes own h(t+1) to buf[(t+1)&1] + publishes; END-barrier.
//
// Unit index in group: q*256 + m*32 + pair (pair = local hid/2, hid =
// q*64 + 2*pair). Publisher: lanes lk<2, even ln (m = lk*4+r).

#define T_ 1024
#define I_ 64
#define H_ 256
#define NGROUP 32
#define NQ 4
#define MB 8      /* batches per group */
#define QH 64     /* hidden units per block (quarter) */
#define HROW 272  /* padded h_lds row (ushorts), 544 B */

#define UNITS_PER_GROUP 1024                       /* 8B units per step */
#define UNITS_PER_PARITY (NGROUP * UNITS_PER_GROUP)
#define SENT_CAP (1 << 16)   /* dead-latch: ~64k sleep-sweeps */

typedef float floatx4 __attribute__((ext_vector_type(4)));
typedef __bf16 bf16x8 __attribute__((ext_vector_type(8)));
typedef unsigned short ushortx8 __attribute__((ext_vector_type(8)));
typedef unsigned int uint32;
typedef unsigned long long u64;

__device__ __forceinline__ float bf2f(uint32 u16) {
  uint32 u = u16 << 16;
  return __builtin_bit_cast(float, u);
}
__device__ __forceinline__ bf16x8 packbf8(floatx4 a, floatx4 b) {
  bf16x8 r;
  r[0] = (__bf16)a[0]; r[1] = (__bf16)a[1];
  r[2] = (__bf16)a[2]; r[3] = (__bf16)a[3];
  r[4] = (__bf16)b[0]; r[5] = (__bf16)b[1];
  r[6] = (__bf16)b[2]; r[7] = (__bf16)b[3];
  return r;
}
__device__ __forceinline__ float fast_sig(float v) {
  return 1.0f / (1.0f + __expf(-v));
}
__device__ __forceinline__ float fast_tanh(float v) {
  float e = __expf(2.0f * v);
  return 1.0f - 2.0f / (e + 1.0f);
}
__device__ __forceinline__ u64 aload64(const u64* p) {
  return __hip_atomic_load(p, __ATOMIC_RELAXED, __HIP_MEMORY_SCOPE_AGENT);
}
__device__ __forceinline__ void astore64(u64* p, u64 v) {
  __hip_atomic_store(p, v, __ATOMIC_RELAXED, __HIP_MEMORY_SCOPE_AGENT);
}

__global__ __launch_bounds__(256, 1) void lstm_main(
    const float* __restrict__ x, const float* __restrict__ W_ih,
    const float* __restrict__ W_hh, const float* __restrict__ b_ih,
    const float* __restrict__ b_hh, u64* __restrict__ units) {
  const int tid = threadIdx.x;
  const int bid = blockIdx.x;
  const int q = bid >> 5;     // quarter 0..3
  const int g = bid & 31;     // group 0..31
  const int wv = tid >> 6;    // wave 0..3 -> 16-hid sub-block
  const int lane = tid & 63;
  const int ln = lane & 15;   // MFMA n (hid) / A row (batch, dup)
  const int lk = lane >> 4;   // MFMA k-subgroup / C row group

  __shared__ __align__(16) unsigned short h_lds[2][MB][HROW];

  const size_t gbase = (size_t)g * UNITS_PER_GROUP;
  // peer quarters, cyclic
  const int q1 = (q + 1) & 3, q2 = (q + 2) & 3, q3 = (q + 3) & 3;

  // zero both h_lds buffers (h_0 = 0; also clears pad)
  {
    uint32* p = (uint32*)&h_lds[0][0][0];
    for (int i = tid; i < 2 * MB * HROW / 2; i += 256) p[i] = 0u;
  }

  // ---- preload weight B-fragments (bf16) + bias, once ----
  // wave wv owns rows j*256 + q*64 + wv*16 + ln, ALL 4 gates j.
  // kc slots: 0..1 x | 2..3 own quarter | 4..5 q1 | 6..7 q2 | 8..9 q3.
  // h-col base for slot kc (also used by HREAD):
  //   kc<2: n/a; 2,3: q*64+(kc-2)*32; 4..9: q_{1+(kc-4)/2}*64+((kc-4)&1)*32
  bf16x8 wf[4][10];
  float bias[4];
#pragma unroll
  for (int j = 0; j < 4; ++j) {
    const int row = j * 256 + q * QH + wv * 16 + ln;
    bias[j] = b_ih[row] + b_hh[row];
    const float* wih = W_ih + (size_t)row * I_;
    const float* whh = W_hh + (size_t)row * H_;
#pragma unroll
    for (int kc = 0; kc < 10; ++kc) {
      const float* src;
      if (kc < 2)       src = wih + kc * 32 + lk * 8;
      else if (kc < 4)  src = whh + q * QH + (kc - 2) * 32 + lk * 8;
      else if (kc < 6)  src = whh + q1 * QH + (kc - 4) * 32 + lk * 8;
      else if (kc < 8)  src = whh + q2 * QH + (kc - 6) * 32 + lk * 8;
      else              src = whh + q3 * QH + (kc - 8) * 32 + lk * 8;
      floatx4 f0 = *(const floatx4*)src;
      floatx4 f1 = *(const floatx4*)(src + 4);
      wf[j][kc] = packbf8(f0, f1);
    }
  }

  const int mb = ln & 7;                       // batch row (m>=8 duplicates)
  const float* xrow = x + ((size_t)(g * MB + mb)) * T_ * I_ + lk * 8;
  // poll roles: thread tid polls unit tid of each peer quarter
  const int pm = tid >> 5;                     // batch of polled units 0..7
  const int pp2 = 2 * (tid & 31);              // 2*pair
  const int pc1 = q1 * QH + pp2, pc2 = q2 * QH + pp2, pc3 = q3 * QH + pp2;
  // publish roles (lanes lk<2, even ln)
  const int opair = wv * 8 + (ln >> 1);        // local pair within quarter
  const int ocol = q * QH + wv * 16 + ln;      // own h_lds col (ushort)
  // HREAD col bases (runtime scalars, used with static kc offsets)
  const int hb_own = q * QH;
  const int hb1 = q1 * QH, hb2 = q2 * QH, hb3 = q3 * QH;

  floatx4 c_reg = (floatx4){0.f, 0.f, 0.f, 0.f};

  // preload x_0
  floatx4 xf0, xf1, xf2, xf3;
  xf0 = *(const floatx4*)(xrow);
  xf1 = *(const floatx4*)(xrow + 4);
  xf2 = *(const floatx4*)(xrow + 32);
  xf3 = *(const floatx4*)(xrow + 36);

  __syncthreads();

#define HREAD(BASE, OFF)                                                    \
  __builtin_bit_cast(bf16x8, *(const ushortx8*)(hrow + (BASE) + (OFF)*32 + \
                                                lk * 8))
#define MFMA4(A, KC)                                                        \
  _Pragma("unroll") for (int j = 0; j < 4; ++j) acc[j] =                    \
      __builtin_amdgcn_mfma_f32_16x16x32_bf16((A), wf[j][KC], acc[j], 0, 0, \
                                              0);

#pragma unroll 1
  for (int t = 0; t < T_; ++t) {
    bf16x8 a0 = packbf8(xf0, xf1);
    bf16x8 a1 = packbf8(xf2, xf3);
    {  // prefetch x_{t+1} (clamped; hides under Phase A + poll)
      const int tn = (t + 1 < T_) ? (t + 1) : t;
      const float* src = xrow + (size_t)tn * I_;
      xf0 = *(const floatx4*)(src);
      xf1 = *(const floatx4*)(src + 4);
      xf2 = *(const floatx4*)(src + 32);
      xf3 = *(const floatx4*)(src + 36);
    }

    // issue poll probes BEFORE Phase A so they fly under the MFMAs
    u64* ub = units + (size_t)(t & 1) * UNITS_PER_PARITY + gbase;
    u64* up1 = ub + q1 * 256 + tid;
    u64* up2 = ub + q2 * 256 + tid;
    u64* up3 = ub + q3 * 256 + tid;
    u64 v1 = 0, v2 = 0, v3 = 0;
    if (t > 0) {
      v1 = aload64(up1);
      v2 = aload64(up2);
      v3 = aload64(up3);
    }

    // ---- Phase A: bias + x + OWN quarter (local, from buf[t&1]) ----
    const unsigned short* hrow = &h_lds[t & 1][mb][0];
    floatx4 acc[4];
#pragma unroll
    for (int j = 0; j < 4; ++j)
      acc[j] = (floatx4){bias[j], bias[j], bias[j], bias[j]};
    MFMA4(a0, 0)
    MFMA4(a1, 1)
    { bf16x8 a = HREAD(hb_own, 0); MFMA4(a, 2) }
    { bf16x8 a = HREAD(hb_own, 1); MFMA4(a, 3) }

    // ---- quiet pipelined poll for the 3 peer quarters of h_t ----
    if (t > 0) {
      bool ok = ((uint32)(v1 >> 32) == (uint32)t) &
                ((uint32)(v2 >> 32) == (uint32)t) &
                ((uint32)(v3 >> 32) == (uint32)t);
      int it = 0;
      while (!__all(ok) && ++it < SENT_CAP) {
        u64 n1 = 0, n2 = 0, n3 = 0;
        if (!ok) {
          n1 = aload64(up1);
          n2 = aload64(up2);
          n3 = aload64(up3);
        }
        __builtin_amdgcn_s_sleep(1);
        if (!ok) {
          v1 = n1; v2 = n2; v3 = n3;
          ok = ((uint32)(v1 >> 32) == (uint32)t) &
               ((uint32)(v2 >> 32) == (uint32)t) &
               ((uint32)(v3 >> 32) == (uint32)t);
        }
      }
      // capture payloads into current read-buffer (peer cols, disjoint
      // from Phase A's own-col reads)
      unsigned short* hw = &h_lds[t & 1][pm][0];
      *(uint32*)(hw + pc1) = (uint32)v1;
      *(uint32*)(hw + pc2) = (uint32)v2;
      *(uint32*)(hw + pc3) = (uint32)v3;
    }
    __syncthreads();  // MID: peer quarters of buf[t&1] ready

    // ---- Phase C: peer-quarter MFMAs (serial path after detect) ----
    { bf16x8 a = HREAD(hb1, 0); MFMA4(a, 4) }
    { bf16x8 a = HREAD(hb1, 1); MFMA4(a, 5) }
    { bf16x8 a = HREAD(hb2, 0); MFMA4(a, 6) }
    { bf16x8 a = HREAD(hb2, 1); MFMA4(a, 7) }
    { bf16x8 a = HREAD(hb3, 0); MFMA4(a, 8) }
    { bf16x8 a = HREAD(hb3, 1); MFMA4(a, 9) }

    // ---- in-register nonlinearity + c/h update; publish ASAP ----
    if (lk < 2) {
      floatx4 iv, fv, gv, ov;
#pragma unroll
      for (int r = 0; r < 4; ++r) {
        iv[r] = fast_sig(acc[0][r]);
        fv[r] = fast_sig(acc[1][r]);
        gv[r] = fast_tanh(acc[2][r]);
        ov[r] = fast_sig(acc[3][r]);
      }
      c_reg = fv * c_reg + iv * gv;
#pragma unroll
      for (int r = 0; r < 4; ++r) {
        float hv = ov[r] * fast_tanh(c_reg[r]);
        unsigned short hb = __builtin_bit_cast(unsigned short, (__bf16)hv);
        int pv = __shfl_xor((int)hb, 1);  // partner ln^1, same lk
        if ((ln & 1) == 0) {
          const int m = lk * 4 + r;  // batch row 0..7
          uint32 dword = (uint32)hb | ((uint32)(unsigned short)pv << 16);
          u64 val = (u64)dword | ((u64)(uint32)(t + 1) << 32);
          const size_t uoff = gbase + (size_t)(q * 256 + m * 32 + opair);
          if (t == T_ - 1) {
            // final h -> clean region (never polled, never RMW'd)
            astore64(units + 2 * (size_t)UNITS_PER_PARITY + uoff, val);
          } else {
            astore64(units + (size_t)((t + 1) & 1) * UNITS_PER_PARITY + uoff,
                     val);
            // own quarter -> next read-buffer
            *(uint32*)&h_lds[(t + 1) & 1][m][ocol] = dword;
          }
        }
      }
    }
    __syncthreads();  // END: buf[(t+1)&1] own cols ready for Phase A(t+1)
  }
#undef HREAD
#undef MFMA4
}

// out[b] = dot(h_T[b], fc_w) + fc_b. Final h lives in the clean region at
// offset 2*UPP. Agent loads -> fresh across replays, no flush dependency.
__global__ void lstm_fc(const u64* __restrict__ units,
                        const float* __restrict__ fc_w,
                        const float* __restrict__ fc_b,
                        float* __restrict__ out) {
  const int b = threadIdx.x;
  const int g = b >> 3, m = b & 7;
  const u64* base =
      units + 2 * (size_t)UNITS_PER_PARITY + (size_t)g * UNITS_PER_GROUP;
  float sum = fc_b[0];
#pragma unroll 4
  for (int u = 0; u < 128; ++u) {
    const int qq = u >> 5, p = u & 31;
    u64 v = aload64(base + qq * 256 + m * 32 + p);
    uint32 lo = (uint32)v;
    const int d = qq * QH + 2 * p;
    sum += bf2f(lo & 0xffffu) * fc_w[d] + bf2f(lo >> 16) * fc_w[d + 1];
  }
  out[b] = sum;
}

extern "C" void kernel_launch(void* const* d_in, const int* in_sizes, int n_in,
                              void* d_out, int out_size, void* d_ws,
                              size_t ws_size, hipStream_t stream) {
  const float* x    = (const float*)d_in[0];
  const float* W_ih = (const float*)d_in[1];
  const float* W_hh = (const float*)d_in[2];
  const float* b_ih = (const float*)d_in[3];
  const float* b_hh = (const float*)d_in[4];
  const float* fc_w = (const float*)d_in[5];
  const float* fc_b = (const float*)d_in[6];
  float* out = (float*)d_out;

  u64* units = (u64*)d_ws;  // 2 parities + final region: 3*256KB = 768KB ws
  // tag poison 0xAAAAAAAA != any live tag (1..1024) => no init needed.

  lstm_main<<<dim3(NGROUP * NQ), dim3(256), 0, stream>>>(
      x, W_ih, W_hh, b_ih, b_hh, units);
  lstm_fc<<<dim3(1), dim3(256), 0, stream>>>(units, fc_w, fc_b, out);
}